// Round 1
// baseline (2797.299 us; speedup 1.0000x reference)
//
#include <hip/hip_runtime.h>

#define B_TOT 2048
#define T_SEQ 256
#define F_IN  64
#define H     35
#define G4    140          // 4*H gate rows
#define NE    8            // batch elements per block
#define BD    280          // NE * H threads
#define HP    36           // h vector padded to /4
#define KA    (F_IN + HP)  // 100 input rows for layer0 (x|h0)
#define KB    (HP + HP)    // 72 input rows for layer1 (h0|h1)

// LDS layout (float offsets)
#define OFF_WA  0
#define SZ_WA   (KA*G4)          // 14000
#define OFF_WB  (OFF_WA + SZ_WA)
#define SZ_WB   (KB*G4)          // 10080
#define OFF_BA  (OFF_WB + SZ_WB) // 24080
#define OFF_BB  (OFF_BA + G4)    // 24220
#define OFF_FCW (OFF_BB + G4)    // 24360
#define SZ_FCW  (HP*F_IN)        // 2304
#define OFF_FCB (OFF_FCW + SZ_FCW) // 26664
#define OFF_XB  (OFF_FCB + F_IN)   // 26728
#define SZ_XB   (NE*F_IN)          // 512
#define OFF_H0  (OFF_XB + SZ_XB)   // 27240
#define SZ_H    (2*NE*HP)          // 576 (double-buffered)
#define OFF_H1  (OFF_H0 + SZ_H)    // 27816
#define SMEM_FLOATS (OFF_H1 + SZ_H) // 28392 floats = 113568 B

#define FMA4(acc, s, w) { acc.x += (s)*(w).x; acc.y += (s)*(w).y; \
                          acc.z += (s)*(w).z; acc.w += (s)*(w).w; }

__device__ __forceinline__ float rcpf_(float x) { return __builtin_amdgcn_rcpf(x); }
__device__ __forceinline__ float sigf(float x)  { return rcpf_(1.0f + __expf(-x)); }
__device__ __forceinline__ float tanhf_(float x){ return 2.0f*rcpf_(1.0f + __expf(-2.0f*x)) - 1.0f; }

extern "C" __global__ void __launch_bounds__(BD)
lstm_all(const float* __restrict__ batch,
         const float* __restrict__ e0_Wih, const float* __restrict__ e0_Whh, const float* __restrict__ e0_b,
         const float* __restrict__ e1_Wih, const float* __restrict__ e1_Whh, const float* __restrict__ e1_b,
         const float* __restrict__ d0_Wih, const float* __restrict__ d0_Whh, const float* __restrict__ d0_b,
         const float* __restrict__ d1_Wih, const float* __restrict__ d1_Whh, const float* __restrict__ d1_b,
         const float* __restrict__ fc_W, const float* __restrict__ fc_b,
         float* __restrict__ out)
{
    extern __shared__ float sm[];
    float* Wa  = sm + OFF_WA;   // [KA][140] permuted: Wa[k][4u+g] = W_{gate g, unit u}[k]
    float* Wb  = sm + OFF_WB;   // [KB][140]
    float* ba  = sm + OFF_BA;   // [140] permuted bias
    float* bb  = sm + OFF_BB;
    float* fcw = sm + OFF_FCW;  // [HP][64]: fcw[u][n] = fc_W[n][u] (u>=H -> 0)
    float* fcb = sm + OFF_FCB;
    float* xb  = sm + OFF_XB;   // [NE][64] current layer-0 input
    float* h0b = sm + OFF_H0;   // [2][NE][HP]
    float* h1b = sm + OFF_H1;   // [2][NE][HP]

    const int tid = threadIdx.x;
    const int e   = tid / H;        // 0..7
    const int u   = tid - e*H;      // 0..34
    const int bE  = blockIdx.x * NE;

    auto load_l0 = [&](const float* Wih, const float* Whh, const float* bias) {
        for (int i = tid; i < KA*G4; i += BD) {
            int k = i / G4, j = i - k*G4;
            int uu = j >> 2, g = j & 3, r = g*H + uu;
            float v = 0.0f;
            if (k < F_IN) v = Wih[r*F_IN + k];
            else { int kk = k - F_IN; if (kk < H) v = Whh[r*H + kk]; }
            Wa[i] = v;
        }
        for (int i = tid; i < G4; i += BD) {
            int uu = i >> 2, g = i & 3;
            ba[i] = bias[g*H + uu];
        }
    };
    auto load_l1 = [&](const float* Wih, const float* Whh, const float* bias) {
        for (int i = tid; i < KB*G4; i += BD) {
            int k = i / G4, j = i - k*G4;
            int uu = j >> 2, g = j & 3, r = g*H + uu;
            float v = 0.0f;
            if (k < HP) { if (k < H) v = Wih[r*H + k]; }
            else { int kk = k - HP; if (kk < H) v = Whh[r*H + kk]; }
            Wb[i] = v;
        }
        for (int i = tid; i < G4; i += BD) {
            int uu = i >> 2, g = i & 3;
            bb[i] = bias[g*H + uu];
        }
    };

    // one-time loads
    load_l0(e0_Wih, e0_Whh, e0_b);
    load_l1(e1_Wih, e1_Whh, e1_b);
    for (int i = tid; i < HP*F_IN; i += BD) {
        int uu = i >> 6, n = i & 63;
        fcw[i] = (uu < H) ? fc_W[n*H + uu] : 0.0f;
    }
    for (int i = tid; i < F_IN; i += BD) fcb[i] = fc_b[i];
    for (int i = tid; i < 2*NE*HP; i += BD) { h0b[i] = 0.0f; h1b[i] = 0.0f; }

    float c0 = 0.0f, c1 = 0.0f;
    int p = 0;

    const float4* Wa4 = (const float4*)Wa;   // [KA][H] float4 quads
    const float4* Wb4 = (const float4*)Wb;   // [KB][H]

    auto layer0 = [&]() {
        float4 acc = ((const float4*)ba)[u];
        const float4* xv4 = (const float4*)(xb + e*F_IN);
        #pragma unroll
        for (int k4 = 0; k4 < F_IN/4; k4++) {
            float4 xv = xv4[k4];
            float4 w;
            w = Wa4[(4*k4+0)*H + u]; FMA4(acc, xv.x, w);
            w = Wa4[(4*k4+1)*H + u]; FMA4(acc, xv.y, w);
            w = Wa4[(4*k4+2)*H + u]; FMA4(acc, xv.z, w);
            w = Wa4[(4*k4+3)*H + u]; FMA4(acc, xv.w, w);
        }
        const float4* h0p4 = (const float4*)(h0b + (p*NE + e)*HP);
        #pragma unroll
        for (int k4 = 0; k4 < HP/4; k4++) {
            float4 hv = h0p4[k4];
            float4 w;
            w = Wa4[(F_IN + 4*k4+0)*H + u]; FMA4(acc, hv.x, w);
            w = Wa4[(F_IN + 4*k4+1)*H + u]; FMA4(acc, hv.y, w);
            w = Wa4[(F_IN + 4*k4+2)*H + u]; FMA4(acc, hv.z, w);
            w = Wa4[(F_IN + 4*k4+3)*H + u]; FMA4(acc, hv.w, w);
        }
        float iv = sigf(acc.x), fv = sigf(acc.y);
        float gv = tanhf_(acc.z), ov = sigf(acc.w);
        c0 = fv*c0 + iv*gv;
        float hn = ov*tanhf_(c0);
        h0b[((p^1)*NE + e)*HP + u] = hn;
    };

    auto layer1 = [&]() {
        float4 acc = ((const float4*)bb)[u];
        const float4* h0n4 = (const float4*)(h0b + ((p^1)*NE + e)*HP);
        #pragma unroll
        for (int k4 = 0; k4 < HP/4; k4++) {
            float4 hv = h0n4[k4];
            float4 w;
            w = Wb4[(4*k4+0)*H + u]; FMA4(acc, hv.x, w);
            w = Wb4[(4*k4+1)*H + u]; FMA4(acc, hv.y, w);
            w = Wb4[(4*k4+2)*H + u]; FMA4(acc, hv.z, w);
            w = Wb4[(4*k4+3)*H + u]; FMA4(acc, hv.w, w);
        }
        const float4* h1p4 = (const float4*)(h1b + (p*NE + e)*HP);
        #pragma unroll
        for (int k4 = 0; k4 < HP/4; k4++) {
            float4 hv = h1p4[k4];
            float4 w;
            w = Wb4[(HP + 4*k4+0)*H + u]; FMA4(acc, hv.x, w);
            w = Wb4[(HP + 4*k4+1)*H + u]; FMA4(acc, hv.y, w);
            w = Wb4[(HP + 4*k4+2)*H + u]; FMA4(acc, hv.z, w);
            w = Wb4[(HP + 4*k4+3)*H + u]; FMA4(acc, hv.w, w);
        }
        float iv = sigf(acc.x), fv = sigf(acc.y);
        float gv = tanhf_(acc.z), ov = sigf(acc.w);
        c1 = fv*c1 + iv*gv;
        float hn = ov*tanhf_(c1);
        h1b[((p^1)*NE + e)*HP + u] = hn;
    };

    auto load_x = [&](int t) {
        for (int i = tid; i < NE*F_IN; i += BD) {
            int ee = i >> 6, k = i & 63;
            xb[i] = batch[((size_t)(bE + ee)*T_SEQ + t)*F_IN + k];
        }
    };

    // ---------------- encoder ----------------
    load_x(0);
    __syncthreads();
    for (int t = 0; t < T_SEQ; t++) {
        layer0();
        __syncthreads();
        layer1();
        if (t + 1 < T_SEQ) load_x(t + 1);   // overlaps with layer1 epoch; xb free after prev barrier
        p ^= 1;
        __syncthreads();
    }

    // ---------------- decoder ----------------
    load_l0(d0_Wih, d0_Whh, d0_b);
    load_l1(d1_Wih, d1_Whh, d1_b);
    for (int i = tid; i < NE*F_IN; i += BD) xb[i] = 0.0f;  // first decoder input = zeros
    __syncthreads();

    for (int s = 0; s < T_SEQ; s++) {
        layer0();
        __syncthreads();
        layer1();
        __syncthreads();
        // fc: pred = h1_new @ fc_W.T + fc_b ; feed back + store reversed
        for (int i = tid; i < NE*F_IN; i += BD) {
            int ee = i >> 6, n = i & 63;
            const float* h1n = h1b + ((p^1)*NE + ee)*HP;
            float acc = fcb[n];
            #pragma unroll
            for (int uu = 0; uu < H; uu++) acc += h1n[uu] * fcw[uu*F_IN + n];
            xb[i] = acc;
            out[((size_t)(bE + ee)*T_SEQ + (T_SEQ - 1 - s))*F_IN + n] = acc;
        }
        p ^= 1;
        __syncthreads();
    }
}

extern "C" void kernel_launch(void* const* d_in, const int* in_sizes, int n_in,
                              void* d_out, int out_size, void* d_ws, size_t ws_size,
                              hipStream_t stream) {
    const float* batch  = (const float*)d_in[0];
    const float* e0_Wih = (const float*)d_in[1];
    const float* e0_Whh = (const float*)d_in[2];
    const float* e0_b   = (const float*)d_in[3];
    const float* e1_Wih = (const float*)d_in[4];
    const float* e1_Whh = (const float*)d_in[5];
    const float* e1_b   = (const float*)d_in[6];
    const float* d0_Wih = (const float*)d_in[7];
    const float* d0_Whh = (const float*)d_in[8];
    const float* d0_b   = (const float*)d_in[9];
    const float* d1_Wih = (const float*)d_in[10];
    const float* d1_Whh = (const float*)d_in[11];
    const float* d1_b   = (const float*)d_in[12];
    const float* fc_W   = (const float*)d_in[13];
    const float* fc_b   = (const float*)d_in[14];
    float* out = (float*)d_out;

    const size_t smem = (size_t)SMEM_FLOATS * sizeof(float);
    // >64KB dynamic LDS: raise the limit (idempotent, host-side, capture-safe)
    (void)hipFuncSetAttribute((const void*)lstm_all,
                              hipFuncAttributeMaxDynamicSharedMemorySize, (int)smem);

    hipLaunchKernelGGL(lstm_all, dim3(B_TOT / NE), dim3(BD), smem, stream,
                       batch, e0_Wih, e0_Whh, e0_b, e1_Wih, e1_Whh, e1_b,
                       d0_Wih, d0_Whh, d0_b, d1_Wih, d1_Whh, d1_b, fc_W, fc_b, out);
}

// Round 2
// 814.369 us; speedup vs baseline: 3.4349x; 3.4349x over previous
//
#include <hip/hip_runtime.h>

#define T_SEQ 256
#define F_IN  64
#define H     35
#define G4    140        // 4*H gate columns (j = 4u+g permuted)
#define NE    8          // batch elements per block
#define BD    320        // 5 waves
#define KP    128        // padded K per acts row (bf16 elems)
#define GP    148        // gates row stride (f32, padded vs bank conflicts)

typedef __attribute__((ext_vector_type(8))) short bf16x8;
typedef __attribute__((ext_vector_type(4))) float f32x4;

__device__ __forceinline__ unsigned short bf16rne(float x) {
    unsigned u = __float_as_uint(x);
    return (unsigned short)((u + 0x7FFFu + ((u >> 16) & 1u)) >> 16);
}
__device__ __forceinline__ float bf16tof(unsigned short h) {
    return __uint_as_float(((unsigned)h) << 16);
}
__device__ __forceinline__ float rcpf_(float x) { return __builtin_amdgcn_rcpf(x); }
__device__ __forceinline__ float sigf(float x)  { return rcpf_(1.0f + __expf(-x)); }
__device__ __forceinline__ float tanhf_(float x){ return 2.0f*rcpf_(1.0f + __expf(-2.0f*x)) - 1.0f; }

// XOR-swizzled byte address into a [16][KP] bf16 acts tile (row stride 256B).
// G4 pattern: byte ^= ((row&7)<<4) — breaks the 16-row same-bank aliasing.
__device__ __forceinline__ char* aswz(char* base, int row, int byteinrow) {
    return base + ((row * 256 + byteinrow) ^ ((row & 7) << 4));
}

extern "C" __global__ void __launch_bounds__(BD, 1)
lstm_mfma(const float* __restrict__ batch,
          const float* __restrict__ e0_Wih, const float* __restrict__ e0_Whh, const float* __restrict__ e0_b,
          const float* __restrict__ e1_Wih, const float* __restrict__ e1_Whh, const float* __restrict__ e1_b,
          const float* __restrict__ d0_Wih, const float* __restrict__ d0_Whh, const float* __restrict__ d0_b,
          const float* __restrict__ d1_Wih, const float* __restrict__ d1_Whh, const float* __restrict__ d1_b,
          const float* __restrict__ fc_W, const float* __restrict__ fc_b,
          float* __restrict__ out)
{
    // acts rows: row = 2e + s (s=0: hi bf16, s=1: lo bf16), e = 0..7
    // acts0 k-layout: [x 0..63 | h0 64..98 | 0-pad]
    // acts1 k-layout: [h0new 0..34 | 0-pad | h1 48..82 | 0-pad]  (fc reads k 48..111)
    __shared__ unsigned short acts0[16 * KP];
    __shared__ unsigned short acts1[16 * KP];
    __shared__ float gates0[8 * GP];
    __shared__ float gates1[8 * GP];
    __shared__ float bias0[144];
    __shared__ float bias1[144];

    const int tid  = threadIdx.x;
    const int wave = tid >> 6;       // 0..4
    const int lane = tid & 63;
    const int l16  = lane & 15;
    const int chk  = lane >> 4;      // k-chunk / C-row-quad select, 0..3
    const int e0c  = 2 * chk;        // element for C regs 0,1
    const int e1c  = 2 * chk + 1;    // element for C regs 2,3
    const int bE   = blockIdx.x * NE;

    // update-phase mapping (one (e,u) per thread, 280 active)
    const bool upd_act = tid < 280;
    const int eu_e = tid / 35;
    const int eu_u = tid - eu_e * 35;

    // x-staging mapping (256 active)
    const bool xs_act = tid < 256;
    const int xs_e = tid >> 5;
    const int xs_p = (tid & 31) * 2;

    // ---- register-resident weight fragments (hi/lo bf16 chains) ----
    bf16x8 B0h[2][4], B0l[2][4];     // layer0: 2 N-slots x 4 K-tiles
    bf16x8 B1h[2][3], B1l[2][3];     // layer1: 2 N-slots x 3 K-tiles
    bf16x8 FCh[2],    FCl[2];        // fc: 1 N-tile (=wave) x 2 K-tiles
    float fcb_r = (wave < 4) ? fc_b[wave * 16 + l16] : 0.0f;

    auto fillfrag = [&](bf16x8& fh, bf16x8& fl, int col, int kbase, int layer,
                        const float* Wih, const float* Whh) {
        #pragma unroll
        for (int j = 0; j < 8; j++) {
            int k = kbase + j;
            float w = 0.0f;
            if (col < G4) {
                int uu = col >> 2, g = col & 3, r = g * H + uu;
                if (layer == 0) {
                    if (k < F_IN) w = Wih[r * F_IN + k];
                    else if (k < F_IN + H) w = Whh[r * H + (k - F_IN)];
                } else {
                    if (k < H) w = Wih[r * H + k];
                    else if (k >= 48 && k < 48 + H) w = Whh[r * H + (k - 48)];
                }
            }
            unsigned short hb = bf16rne(w);
            fh[j] = (short)hb;
            fl[j] = (short)bf16rne(w - bf16tof(hb));
        }
    };

    auto load_weights = [&](const float* W0i, const float* W0h, const float* b0p,
                            const float* W1i, const float* W1h, const float* b1p) {
        #pragma unroll
        for (int s = 0; s < 2; s++) {
            int col = (2 * wave + s) * 16 + l16;
            #pragma unroll
            for (int kt = 0; kt < 4; kt++)
                fillfrag(B0h[s][kt], B0l[s][kt], col, kt * 32 + chk * 8, 0, W0i, W0h);
            #pragma unroll
            for (int kt = 0; kt < 3; kt++)
                fillfrag(B1h[s][kt], B1l[s][kt], col, kt * 32 + chk * 8, 1, W1i, W1h);
        }
        for (int i = tid; i < G4; i += BD) {
            int uu = i >> 2, g = i & 3;
            bias0[i] = b0p[g * H + uu];
            bias1[i] = b1p[g * H + uu];
        }
    };

    // ---- MFMA phases ----
    auto phase_l0 = [&]() {
        bf16x8 a[4];
        #pragma unroll
        for (int kt = 0; kt < 4; kt++)
            a[kt] = *(const bf16x8*)aswz((char*)acts0, l16, kt * 64 + chk * 16);
        #pragma unroll
        for (int s = 0; s < 2; s++) {
            int nt = 2 * wave + s;
            if (nt < 9) {
                f32x4 ch = {0.f,0.f,0.f,0.f}, cl = {0.f,0.f,0.f,0.f};
                #pragma unroll
                for (int kt = 0; kt < 4; kt++) {
                    ch = __builtin_amdgcn_mfma_f32_16x16x32_bf16(a[kt], B0h[s][kt], ch, 0, 0, 0);
                    cl = __builtin_amdgcn_mfma_f32_16x16x32_bf16(a[kt], B0l[s][kt], cl, 0, 0, 0);
                }
                int col = nt * 16 + l16;
                gates0[e0c * GP + col] = ch[0] + ch[1] + cl[0] + cl[1];
                gates0[e1c * GP + col] = ch[2] + ch[3] + cl[2] + cl[3];
            }
        }
    };

    auto phase_l1 = [&]() {
        bf16x8 a[3];
        #pragma unroll
        for (int kt = 0; kt < 3; kt++)
            a[kt] = *(const bf16x8*)aswz((char*)acts1, l16, kt * 64 + chk * 16);
        #pragma unroll
        for (int s = 0; s < 2; s++) {
            int nt = 2 * wave + s;
            if (nt < 9) {
                f32x4 ch = {0.f,0.f,0.f,0.f}, cl = {0.f,0.f,0.f,0.f};
                #pragma unroll
                for (int kt = 0; kt < 3; kt++) {
                    ch = __builtin_amdgcn_mfma_f32_16x16x32_bf16(a[kt], B1h[s][kt], ch, 0, 0, 0);
                    cl = __builtin_amdgcn_mfma_f32_16x16x32_bf16(a[kt], B1l[s][kt], cl, 0, 0, 0);
                }
                int col = nt * 16 + l16;
                gates1[e0c * GP + col] = ch[0] + ch[1] + cl[0] + cl[1];
                gates1[e1c * GP + col] = ch[2] + ch[3] + cl[2] + cl[3];
            }
        }
    };

    float c0 = 0.0f, c1 = 0.0f;

    auto update = [&](float* gts, float* bias, float& c, int hk0, int hk1) {
        if (upd_act) {
            float4 g4 = *(const float4*)&gts[eu_e * GP + 4 * eu_u];
            float4 b4 = *(const float4*)&bias[4 * eu_u];
            float iv = sigf(g4.x + b4.x);
            float fv = sigf(g4.y + b4.y);
            float gv = tanhf_(g4.z + b4.z);
            float ov = sigf(g4.w + b4.w);
            c = fv * c + iv * gv;
            float h = ov * tanhf_(c);
            unsigned short hh = bf16rne(h);
            unsigned short hl = bf16rne(h - bf16tof(hh));
            if (hk0 >= 0) {
                *(unsigned short*)aswz((char*)acts0, 2 * eu_e,     2 * (hk0 + eu_u)) = hh;
                *(unsigned short*)aswz((char*)acts0, 2 * eu_e + 1, 2 * (hk0 + eu_u)) = hl;
            }
            *(unsigned short*)aswz((char*)acts1, 2 * eu_e,     2 * (hk1 + eu_u)) = hh;
            *(unsigned short*)aswz((char*)acts1, 2 * eu_e + 1, 2 * (hk1 + eu_u)) = hl;
        }
    };

    auto write_x = [&](float a, float b) {
        unsigned short ah = bf16rne(a), bh = bf16rne(b);
        unsigned short al = bf16rne(a - bf16tof(ah)), bl = bf16rne(b - bf16tof(bh));
        unsigned ph = (unsigned)ah | ((unsigned)bh << 16);
        unsigned pl = (unsigned)al | ((unsigned)bl << 16);
        *(unsigned*)aswz((char*)acts0, 2 * xs_e,     2 * xs_p) = ph;
        *(unsigned*)aswz((char*)acts0, 2 * xs_e + 1, 2 * xs_p) = pl;
    };

    // ================= init =================
    for (int i = tid; i < 16 * KP; i += BD) { acts0[i] = 0; acts1[i] = 0; }
    load_weights(e0_Wih, e0_Whh, e0_b, e1_Wih, e1_Whh, e1_b);
    if (wave < 4) {
        int col = wave * 16 + l16;
        #pragma unroll
        for (int i = 0; i < 2; i++) {
            bf16x8 fh, fl;
            #pragma unroll
            for (int j = 0; j < 8; j++) {
                int k = 48 + 32 * i + chk * 8 + j;
                float w = (k >= 48 && k < 48 + H) ? fc_W[col * H + (k - 48)] : 0.0f;
                unsigned short hb = bf16rne(w);
                fh[j] = (short)hb;
                fl[j] = (short)bf16rne(w - bf16tof(hb));
            }
            FCh[i] = fh; FCl[i] = fl;
        }
    }
    __syncthreads();

    // stage x(0)
    if (xs_act) {
        const float2 v = *(const float2*)&batch[((size_t)(bE + xs_e) * T_SEQ + 0) * F_IN + xs_p];
        write_x(v.x, v.y);
    }
    __syncthreads();

    // ================= encoder =================
    #pragma unroll 1
    for (int t = 0; t < T_SEQ; t++) {
        float nxa = 0.f, nxb = 0.f;
        if (t + 1 < T_SEQ && xs_act) {
            const float2 v = *(const float2*)&batch[((size_t)(bE + xs_e) * T_SEQ + (t + 1)) * F_IN + xs_p];
            nxa = v.x; nxb = v.y;
        }
        phase_l0();
        __syncthreads();
        update(gates0, bias0, c0, 64, 0);
        __syncthreads();
        phase_l1();
        __syncthreads();
        update(gates1, bias1, c1, -1, 48);
        if (t + 1 < T_SEQ && xs_act) write_x(nxa, nxb);
        __syncthreads();
    }

    // ================= transition =================
    load_weights(d0_Wih, d0_Whh, d0_b, d1_Wih, d1_Whh, d1_b);
    for (int i = tid; i < 16 * 64; i += BD) {   // zero x region (decoder temp = 0)
        int row = i >> 6, k = i & 63;
        acts0[row * KP + k] = 0;
    }
    __syncthreads();

    // ================= decoder =================
    #pragma unroll 1
    for (int s = 0; s < T_SEQ; s++) {
        phase_l0();
        __syncthreads();
        update(gates0, bias0, c0, 64, 0);
        __syncthreads();
        phase_l1();
        __syncthreads();
        update(gates1, bias1, c1, -1, 48);
        __syncthreads();
        // fc: pred = h1 @ fcW.T + fcb, via MFMA on acts1 k=48..111
        if (wave < 4) {
            bf16x8 afc[2];
            #pragma unroll
            for (int i = 0; i < 2; i++)
                afc[i] = *(const bf16x8*)aswz((char*)acts1, l16, 96 + 64 * i + chk * 16);
            f32x4 ch = {0.f,0.f,0.f,0.f}, cl = {0.f,0.f,0.f,0.f};
            #pragma unroll
            for (int i = 0; i < 2; i++) {
                ch = __builtin_amdgcn_mfma_f32_16x16x32_bf16(afc[i], FCh[i], ch, 0, 0, 0);
                cl = __builtin_amdgcn_mfma_f32_16x16x32_bf16(afc[i], FCl[i], cl, 0, 0, 0);
            }
            int col = wave * 16 + l16;
            float p0 = ch[0] + ch[1] + cl[0] + cl[1] + fcb_r;
            float p1 = ch[2] + ch[3] + cl[2] + cl[3] + fcb_r;
            out[((size_t)(bE + e0c) * T_SEQ + (T_SEQ - 1 - s)) * F_IN + col] = p0;
            out[((size_t)(bE + e1c) * T_SEQ + (T_SEQ - 1 - s)) * F_IN + col] = p1;
            // feedback into acts0 x region
            unsigned short h0h = bf16rne(p0);
            unsigned short h0l = bf16rne(p0 - bf16tof(h0h));
            unsigned short h1h = bf16rne(p1);
            unsigned short h1l = bf16rne(p1 - bf16tof(h1h));
            *(unsigned short*)aswz((char*)acts0, 2 * e0c,     2 * col) = h0h;
            *(unsigned short*)aswz((char*)acts0, 2 * e0c + 1, 2 * col) = h0l;
            *(unsigned short*)aswz((char*)acts0, 2 * e1c,     2 * col) = h1h;
            *(unsigned short*)aswz((char*)acts0, 2 * e1c + 1, 2 * col) = h1l;
        }
        __syncthreads();
    }
}

extern "C" void kernel_launch(void* const* d_in, const int* in_sizes, int n_in,
                              void* d_out, int out_size, void* d_ws, size_t ws_size,
                              hipStream_t stream) {
    const float* batch  = (const float*)d_in[0];
    const float* e0_Wih = (const float*)d_in[1];
    const float* e0_Whh = (const float*)d_in[2];
    const float* e0_b   = (const float*)d_in[3];
    const float* e1_Wih = (const float*)d_in[4];
    const float* e1_Whh = (const float*)d_in[5];
    const float* e1_b   = (const float*)d_in[6];
    const float* d0_Wih = (const float*)d_in[7];
    const float* d0_Whh = (const float*)d_in[8];
    const float* d0_b   = (const float*)d_in[9];
    const float* d1_Wih = (const float*)d_in[10];
    const float* d1_Whh = (const float*)d_in[11];
    const float* d1_b   = (const float*)d_in[12];
    const float* fc_W   = (const float*)d_in[13];
    const float* fc_b   = (const float*)d_in[14];
    float* out = (float*)d_out;

    hipLaunchKernelGGL(lstm_mfma, dim3(2048 / NE), dim3(BD), 0, stream,
                       batch, e0_Wih, e0_Whh, e0_b, e1_Wih, e1_Whh, e1_b,
                       d0_Wih, d0_Whh, d0_b, d1_Wih, d1_Whh, d1_b, fc_W, fc_b, out);
}